// Round 2
// baseline (4298.375 us; speedup 1.0000x reference)
//
#include <hip/hip_runtime.h>
#include <cstdint>
#include <cstddef>

#define NBLK 128
#define NT   256
#define ROWS 64
#define DD   100
#define HH   110
#define NS   63
#define NGRP 16
#define GRP  (NBLK / NGRP)
#define SLOTF (NGRP * 256)   // floats per stats region: 16 group-slots x (128 sum | 128 sq)

typedef __bf16 bf16x8 __attribute__((ext_vector_type(8)));
typedef float  f32x16 __attribute__((ext_vector_type(16)));

struct Params {
  const float* W; const float* yini; const float* zini;
  const float* g0; const float* b0; const float* g1; const float* b1;
  const float* g2; const float* b2; const float* g3; const float* b3;
  const float* w0; const float* w1; const float* w2;
  float* out; float* slots; int* cnts;
};

// relaxed agent-scope load: L1/L2-bypass, reads the coherence point (MALL)
__device__ __forceinline__ float agent_ld(const float* p_) {
  return __hip_atomic_load(p_, __ATOMIC_RELAXED, __HIP_MEMORY_SCOPE_AGENT);
}
// relaxed agent-scope store: L1/L2-bypass write to MALL (used to re-zero dead regions)
__device__ __forceinline__ void agent_st(float* p_, float v) {
  __hip_atomic_store(p_, v, __ATOMIC_RELAXED, __HIP_MEMORY_SCOPE_AGENT);
}

// Cache-op-free grid barrier. Stats atomics (agent scope) execute at the MALL;
// s_waitcnt vmcnt(0) guarantees they are acked there before the flag add, so any
// observer of the flag (via L2-bypassing relaxed atomic load) sees final stats.
// Counters are MONOTONIC: barrier g waits for count >= (g+1)*GRP — no reset needed.
__device__ __forceinline__ void sync_arrive(int* cn) {
  asm volatile("s_waitcnt vmcnt(0)" ::: "memory");
  __syncthreads();
  if (threadIdx.x == 0)
    __hip_atomic_fetch_add(&cn[(blockIdx.x & (NGRP - 1)) * 16], 1,
                           __ATOMIC_RELAXED, __HIP_MEMORY_SCOPE_AGENT);
}
__device__ __forceinline__ void sync_wait(int* cn, int target) {
  if (threadIdx.x < NGRP) {
    while (__hip_atomic_load(&cn[threadIdx.x * 16], __ATOMIC_RELAXED,
                             __HIP_MEMORY_SCOPE_AGENT) < target)
      __builtin_amdgcn_s_sleep(1);
  }
  __syncthreads();
  asm volatile("" ::: "memory");
}

// issue B-fragment global loads (w[k][n], masked to zero outside K x N)
template<int K, int N>
__device__ __forceinline__ void issueB(const float* wg, int n, int half, float (*t)[8]) {
#pragma unroll
  for (int c = 0; c < 7; ++c) {
#pragma unroll
    for (int j = 0; j < 8; ++j) {
      int k = c * 16 + half * 8 + j;
      t[c][j] = (k < K && n < N) ? wg[k * N + n] : 0.f;
    }
  }
}

// two 32-row tiles (M=64) sharing the B fragments
__device__ __forceinline__ void run_mfma2(const __bf16* hs, const float (*t)[8],
                                          int col, int half, f32x16* acc) {
  acc[0] = (f32x16)(0.f);
  acc[1] = (f32x16)(0.f);
#pragma unroll
  for (int c = 0; c < 7; ++c) {
    bf16x8 bfv;
#pragma unroll
    for (int j = 0; j < 8; ++j) bfv[j] = (__bf16)t[c][j];
    bf16x8 a0 = *(const bf16x8*)(hs + col * 120 + c * 16 + half * 8);
    bf16x8 a1 = *(const bf16x8*)(hs + (32 + col) * 120 + c * 16 + half * 8);
    acc[0] = __builtin_amdgcn_mfma_f32_32x32x16_bf16(a0, bfv, acc[0], 0, 0, 0);
    acc[1] = __builtin_amdgcn_mfma_f32_32x32x16_bf16(a1, bfv, acc[1], 0, 0, 0);
  }
}

// per-feature partial stats over this block's 64 rows -> THIS GROUP's slot only
// (8-way same-address contention instead of 128-way)
__device__ __forceinline__ void frag_stats(const f32x16* acc, float* myslot,
                                           int n, int N, int half) {
  float sm = 0.f, sq = 0.f;
#pragma unroll
  for (int m = 0; m < 2; ++m)
#pragma unroll
    for (int i = 0; i < 16; ++i) { float v = acc[m][i]; sm += v; sq += v * v; }
  sm += __shfl_xor(sm, 32);
  sq += __shfl_xor(sq, 32);
  if (half == 0 && n < N) {
    atomicAdd(&myslot[n], sm);
    atomicAdd(&myslot[128 + n], sq);
  }
}

// finalize: sum the 16 group partials (independent MALL loads, pipelined)
__device__ __forceinline__ void bn_ac2(const float* reg, const float* gam,
                                       const float* bet, int n, int N, float scale,
                                       float& a, float& c) {
  a = 0.f; c = 0.f;
  if (n < N) {
    float sm = 0.f, sq = 0.f;
#pragma unroll
    for (int g = 0; g < NGRP; ++g) {
      sm += agent_ld(&reg[g * 256 + n]);
      sq += agent_ld(&reg[g * 256 + 128 + n]);
    }
    float mean = sm * (1.f / 8192.f);
    float var  = fmaxf(sq * (1.f / 8192.f) - mean * mean, 0.f);
    float au = gam[n] * rsqrtf(var + 1e-6f);
    a = au * scale;
    c = (bet[n] - mean * au) * scale;
  }
}

__device__ __forceinline__ void write_h(__bf16* hs, const f32x16* acc,
                                        float a, float c, int n, int half) {
  if (n < 112) {
#pragma unroll
    for (int m = 0; m < 2; ++m)
#pragma unroll
      for (int i = 0; i < 16; ++i) {
        int row = m * 32 + (i & 3) + 8 * (i >> 2) + 4 * half;
        float v = fmaxf(acc[m][i] * a + c, 0.f);
        hs[row * 120 + n] = (__bf16)v;
      }
  }
}

__device__ __forceinline__ void write_z(float* zs, const f32x16* acc,
                                        float a, float c, int n, int half) {
  if (n < DD) {
#pragma unroll
    for (int m = 0; m < 2; ++m)
#pragma unroll
      for (int i = 0; i < 16; ++i) {
        int row = m * 32 + (i & 3) + 8 * (i >> 2) + 4 * half;
        zs[row * 104 + n] = acc[m][i] * a + c;
      }
  }
}

__global__ __launch_bounds__(NT) void bsde_kernel(Params p) {
  __shared__ float xs[ROWS * 104];
  __shared__ float zs[ROWS * 104];
  __shared__ float dws[ROWS * 104];
  __shared__ float ys[ROWS];
  __shared__ __bf16 hsb[ROWS * 120];
  __shared__ float aS[128], cS[128];

  const int tid  = threadIdx.x;
  const int lane = tid & 63;
  const int wv   = tid >> 6;
  const int col  = lane & 31;
  const int half = lane >> 5;
  const int n    = wv * 32 + col;
  const int grp  = blockIdx.x & (NGRP - 1);
  const int b0   = blockIdx.x * ROWS;

  // ---- init persistent state ----
  {
    float z0 = p.zini[0];
    for (int i = tid; i < ROWS * 104; i += NT) { xs[i] = 1.57079632679f; zs[i] = z0; }
    if (tid < ROWS) ys[tid] = p.yini[0];
  }
  for (int idx = tid; idx < ROWS * 128; idx += NT) {
    int r = idx >> 7, d = idx & 127;
    if (d < DD) {
      const float* wr = p.W + (size_t)(b0 + r) * 6400 + d;
      dws[r * 104 + d] = wr[100] - wr[0];
    }
  }
  __syncthreads();

  int seg = 0;  // global barrier-segment index (0..251); region = seg % 3

  for (int s = 0; s < NS; ++s) {
    // ---- phase 0: x,y update (block-local) ----
    {
      int r = tid >> 2, l4 = tid & 3;
      float yr = ys[r];
      float ssum = 0.f, zdw = 0.f;
#pragma unroll
      for (int i = 0; i < 25; ++i) {
        int d = l4 + 4 * i;
        float dw = dws[r * 104 + d];
        float xv = xs[r * 104 + d] + 0.3f * dw * yr;
        xs[r * 104 + d] = xv;
        ssum += __sinf(xv);
        zdw  += zs[r * 104 + d] * dw;
      }
      ssum += __shfl_down(ssum, 2, 4);
      ssum += __shfl_down(ssum, 1, 4);
      zdw  += __shfl_down(zdw, 2, 4);
      zdw  += __shfl_down(zdw, 1, 4);
      if (l4 == 0) {
        float ec = __expf(-0.3f * (1.f - (float)s * (1.f / 64.f)));
        float tc = 0.1f * ssum;
        float drift = -0.1f * yr + 0.045f * ec * tc * tc * tc;
        ys[r] = yr - drift * (1.f / 64.f) + zdw;
      }
    }
    __syncthreads();

    // ---- BN0 stats (h = [x | y], 101 features) ----
    float* reg0 = p.slots + (seg % 3) * SLOTF;
    {
      float* my0 = reg0 + grp * 256;
      if (tid < 101) {
        float sm = 0.f, sq = 0.f;
        if (tid < DD) {
          for (int r = 0; r < ROWS; ++r) { float v = xs[r * 104 + tid]; sm += v; sq += v * v; }
        } else {
          for (int r = 0; r < ROWS; ++r) { float v = ys[r]; sm += v; sq += v * v; }
        }
        atomicAdd(&my0[tid], sm);
        atomicAdd(&my0[128 + tid], sq);
      }
    }
    sync_arrive(p.cnts);
    float tB[7][8];
    issueB<101, HH>(p.w0 + (size_t)s * 11110, n, half, tB);   // overlap w/ barrier
    sync_wait(p.cnts, (seg + 1) * GRP);
    // re-zero the dead region (used at seg-1; provably idle until seg+2's adds,
    // which follow barrier seg+1 — our arrive(seg+1) vmcnt(0) flushes this store)
    if (blockIdx.x < NGRP)
      agent_st(&p.slots[((seg + 2) % 3) * SLOTF + (int)blockIdx.x * 256 + tid], 0.f);
    ++seg;
    if (tid < 128) {
      float a = 0.f, c = 0.f;
      if (tid < 101) {
        float sm = 0.f, sq = 0.f;
#pragma unroll
        for (int g = 0; g < NGRP; ++g) {
          sm += agent_ld(&reg0[g * 256 + tid]);
          sq += agent_ld(&reg0[g * 256 + 128 + tid]);
        }
        float mean = sm * (1.f / 8192.f);
        float var  = fmaxf(sq * (1.f / 8192.f) - mean * mean, 0.f);
        float au = p.g0[s * 101 + tid] * rsqrtf(var + 1e-6f);
        a = au; c = p.b0[s * 101 + tid] - mean * au;
      }
      aS[tid] = a; cS[tid] = c;
    }
    __syncthreads();
    for (int idx = tid; idx < ROWS * 128; idx += NT) {
      int r = idx >> 7, d = idx & 127;
      if (d < 112) {
        float v = (d < DD)  ? xs[r * 104 + d] * aS[d] + cS[d]
                : (d == DD) ? ys[r] * aS[DD] + cS[DD] : 0.f;
        hsb[r * 120 + d] = (__bf16)v;
      }
    }
    __syncthreads();

    f32x16 acc[2];
    // ---- L0: h @ w0 -> BN1 -> relu ----
    {
      run_mfma2(hsb, tB, col, half, acc);
      float* reg = p.slots + (seg % 3) * SLOTF;
      frag_stats(acc, reg + grp * 256, n, HH, half);
      sync_arrive(p.cnts);
      issueB<HH, HH>(p.w1 + (size_t)s * 12100, n, half, tB);
      sync_wait(p.cnts, (seg + 1) * GRP);
      if (blockIdx.x < NGRP)
        agent_st(&p.slots[((seg + 2) % 3) * SLOTF + (int)blockIdx.x * 256 + tid], 0.f);
      ++seg;
      float a, c;
      bn_ac2(reg, p.g1 + s * HH, p.b1 + s * HH, n, HH, 1.f, a, c);
      write_h(hsb, acc, a, c, n, half);
      __syncthreads();
    }
    // ---- L1: h @ w1 -> BN2 -> relu ----
    {
      run_mfma2(hsb, tB, col, half, acc);
      float* reg = p.slots + (seg % 3) * SLOTF;
      frag_stats(acc, reg + grp * 256, n, HH, half);
      sync_arrive(p.cnts);
      issueB<HH, DD>(p.w2 + (size_t)s * 11000, n, half, tB);
      sync_wait(p.cnts, (seg + 1) * GRP);
      if (blockIdx.x < NGRP)
        agent_st(&p.slots[((seg + 2) % 3) * SLOTF + (int)blockIdx.x * 256 + tid], 0.f);
      ++seg;
      float a, c;
      bn_ac2(reg, p.g2 + s * HH, p.b2 + s * HH, n, HH, 1.f, a, c);
      write_h(hsb, acc, a, c, n, half);
      __syncthreads();
    }
    // ---- L2: h @ w2 -> BN3 -> z/100  (bias2 zero & batch-constant: cancels in BN) ----
    {
      run_mfma2(hsb, tB, col, half, acc);
      float* reg = p.slots + (seg % 3) * SLOTF;
      frag_stats(acc, reg + grp * 256, n, DD, half);
      sync_arrive(p.cnts);
      if (s + 1 < NS) {   // prefetch next step's dW under the barrier
        for (int idx = tid; idx < ROWS * 128; idx += NT) {
          int r = idx >> 7, d = idx & 127;
          if (d < DD) {
            const float* wr = p.W + (size_t)(b0 + r) * 6400 + (s + 1) * 100 + d;
            dws[r * 104 + d] = wr[100] - wr[0];
          }
        }
      }
      sync_wait(p.cnts, (seg + 1) * GRP);
      if (blockIdx.x < NGRP)
        agent_st(&p.slots[((seg + 2) % 3) * SLOTF + (int)blockIdx.x * 256 + tid], 0.f);
      ++seg;
      float a, c;
      bn_ac2(reg, p.g3 + s * DD, p.b3 + s * DD, n, DD, 0.01f, a, c);
      write_z(zs, acc, a, c, n, half);
      __syncthreads();
    }
  }

  // ---- final extra update with dW[-1] ----
  {
    int r = tid >> 2, l4 = tid & 3;
    float yr = ys[r];
    float ssum = 0.f, zdw = 0.f;
#pragma unroll
    for (int i = 0; i < 25; ++i) {
      int d = l4 + 4 * i;
      float dw = dws[r * 104 + d];
      float xv = xs[r * 104 + d] + 0.3f * dw * yr;
      xs[r * 104 + d] = xv;
      ssum += __sinf(xv);
      zdw  += zs[r * 104 + d] * dw;
    }
    ssum += __shfl_down(ssum, 2, 4);
    ssum += __shfl_down(ssum, 1, 4);
    zdw  += __shfl_down(zdw, 2, 4);
    zdw  += __shfl_down(zdw, 1, 4);
    if (l4 == 0) {
      float ec = __expf(-0.3f * (1.f - 62.f * (1.f / 64.f)));
      float tc = 0.1f * ssum;
      float drift = -0.1f * yr + 0.045f * ec * tc * tc * tc;
      ys[r] = yr - drift * (1.f / 64.f) + zdw;
    }
  }
  __syncthreads();

  // ---- outputs: x [8192,100] then y [8192,1] ----
  for (int idx = tid; idx < ROWS * 128; idx += NT) {
    int r = idx >> 7, d = idx & 127;
    if (d < DD) p.out[(size_t)(b0 + r) * 100 + d] = xs[r * 104 + d];
  }
  if (tid < ROWS) p.out[819200 + b0 + tid] = ys[tid];
}

extern "C" void kernel_launch(void* const* d_in, const int* in_sizes, int n_in,
                              void* d_out, int out_size, void* d_ws, size_t ws_size,
                              hipStream_t stream) {
  Params p;
  p.W    = (const float*)d_in[0];
  p.yini = (const float*)d_in[1];
  p.zini = (const float*)d_in[2];
  p.g0   = (const float*)d_in[3];  p.b0 = (const float*)d_in[4];
  p.g1   = (const float*)d_in[5];  p.b1 = (const float*)d_in[6];
  p.g2   = (const float*)d_in[7];  p.b2 = (const float*)d_in[8];
  p.g3   = (const float*)d_in[9];  p.b3 = (const float*)d_in[10];
  p.w0   = (const float*)d_in[11]; p.w1 = (const float*)d_in[12];
  p.w2   = (const float*)d_in[13];
  p.out   = (float*)d_out;
  p.slots = (float*)d_ws;
  p.cnts  = (int*)((char*)d_ws + (size_t)3 * SLOTF * 4);

  size_t zbytes = (size_t)3 * SLOTF * 4          // 3 rotating stats regions
                + (size_t)NGRP * 16 * 4;         // monotonic group counters
  hipMemsetAsync(d_ws, 0, zbytes, stream);
  bsde_kernel<<<dim3(NBLK), dim3(NT), 0, stream>>>(p);
}

// Round 3
// 3116.327 us; speedup vs baseline: 1.3793x; 1.3793x over previous
//
#include <hip/hip_runtime.h>
#include <cstdint>
#include <cstddef>

#define NBLK 128
#define NT   256
#define ROWS 64
#define DD   100
#define HH   110
#define NS   63
#define NGRP 16
#define GRP  (NBLK / NGRP)
#define REGF 512              // floats per stats region (3 rotating regions)

typedef __bf16 bf16x8 __attribute__((ext_vector_type(8)));
typedef float  f32x16 __attribute__((ext_vector_type(16)));

struct Params {
  const float* W; const float* yini; const float* zini;
  const float* g0; const float* b0; const float* g1; const float* b1;
  const float* g2; const float* b2; const float* g3; const float* b3;
  const float* w0; const float* w1; const float* w2;
  float* out; float* slots; int* cnts;
};

__device__ __forceinline__ float agent_ld(const float* p_) {
  return __hip_atomic_load(p_, __ATOMIC_RELAXED, __HIP_MEMORY_SCOPE_AGENT);
}
__device__ __forceinline__ void agent_st(float* p_, float v) {
  __hip_atomic_store(p_, v, __ATOMIC_RELAXED, __HIP_MEMORY_SCOPE_AGENT);
}

// Cache-op-free grid barrier (proven in prior rounds). Monotonic counters.
__device__ __forceinline__ void sync_arrive(int* cn) {
  asm volatile("s_waitcnt vmcnt(0)" ::: "memory");
  __syncthreads();
  if (threadIdx.x == 0)
    __hip_atomic_fetch_add(&cn[(blockIdx.x & (NGRP - 1)) * 16], 1,
                           __ATOMIC_RELAXED, __HIP_MEMORY_SCOPE_AGENT);
}
__device__ __forceinline__ void sync_wait(int* cn, int target) {
  if (threadIdx.x < NGRP) {
    while (__hip_atomic_load(&cn[threadIdx.x * 16], __ATOMIC_RELAXED,
                             __HIP_MEMORY_SCOPE_AGENT) < target)
      __builtin_amdgcn_s_sleep(1);
  }
  __syncthreads();
  asm volatile("" ::: "memory");
}

// B-fragment global loads (w[k][n], masked to zero outside K x N)
template<int K, int N>
__device__ __forceinline__ void issueB(const float* wg, int n, int half, float (*t)[8]) {
#pragma unroll
  for (int c = 0; c < 7; ++c) {
#pragma unroll
    for (int j = 0; j < 8; ++j) {
      int k = c * 16 + half * 8 + j;
      t[c][j] = (k < K && n < N) ? wg[k * N + n] : 0.f;
    }
  }
}

__device__ __forceinline__ void run_mfma2(const __bf16* hs, const float (*t)[8],
                                          int col, int half, f32x16* acc) {
  acc[0] = (f32x16)(0.f);
  acc[1] = (f32x16)(0.f);
#pragma unroll
  for (int c = 0; c < 7; ++c) {
    bf16x8 bfv;
#pragma unroll
    for (int j = 0; j < 8; ++j) bfv[j] = (__bf16)t[c][j];
    bf16x8 a0 = *(const bf16x8*)(hs + col * 120 + c * 16 + half * 8);
    bf16x8 a1 = *(const bf16x8*)(hs + (32 + col) * 120 + c * 16 + half * 8);
    acc[0] = __builtin_amdgcn_mfma_f32_32x32x16_bf16(a0, bfv, acc[0], 0, 0, 0);
    acc[1] = __builtin_amdgcn_mfma_f32_32x32x16_bf16(a1, bfv, acc[1], 0, 0, 0);
  }
}

// sum/sumsq partials -> flat slot [n], [112+n]
__device__ __forceinline__ void frag2(const f32x16* acc, float* slot, int n, int N, int half) {
  float sm = 0.f, sq = 0.f;
#pragma unroll
  for (int m = 0; m < 2; ++m)
#pragma unroll
    for (int i = 0; i < 16; ++i) { float v = acc[m][i]; sm += v; sq += v * v; }
  sm += __shfl_xor(sm, 32);
  sq += __shfl_xor(sq, 32);
  if (half == 0 && n < N) {
    atomicAdd(&slot[n], sm);
    atomicAdd(&slot[112 + n], sq);
  }
}

// sum/sumsq/sum(m*y) partials -> [n],[112+n],[224+n]  (E barrier)
__device__ __forceinline__ void frag3(const f32x16* acc, float* slot, int n, int half,
                                      const float* ysl) {
  float sm = 0.f, sq = 0.f, sy = 0.f;
#pragma unroll
  for (int m = 0; m < 2; ++m)
#pragma unroll
    for (int i = 0; i < 16; ++i) {
      float v = acc[m][i];
      int row = m * 32 + (i & 3) + 8 * (i >> 2) + 4 * half;
      sm += v; sq += v * v; sy += v * ysl[row];
    }
  sm += __shfl_xor(sm, 32);
  sq += __shfl_xor(sq, 32);
  sy += __shfl_xor(sy, 32);
  if (half == 0 && n < HH) {
    atomicAdd(&slot[n], sm);
    atomicAdd(&slot[112 + n], sq);
    atomicAdd(&slot[224 + n], sy);
  }
}

__device__ __forceinline__ void finalize2(const float* slot, const float* gam,
                                          const float* bet, int n, int N, float scale,
                                          float& a, float& c) {
  a = 0.f; c = 0.f;
  if (n < N) {
    float sm = agent_ld(&slot[n]);
    float sq = agent_ld(&slot[112 + n]);
    float mean = sm * (1.f / 8192.f);
    float var  = fmaxf(sq * (1.f / 8192.f) - mean * mean, 0.f);
    float au = gam[n] * rsqrtf(var + 1e-6f);
    a = au * scale;
    c = (bet[n] - mean * au) * scale;
  }
}

__device__ __forceinline__ void write_h(__bf16* hs, const f32x16* acc,
                                        float a, float c, int n, int half) {
  if (n < 112) {
#pragma unroll
    for (int m = 0; m < 2; ++m)
#pragma unroll
      for (int i = 0; i < 16; ++i) {
        int row = m * 32 + (i & 3) + 8 * (i >> 2) + 4 * half;
        float v = fmaxf(acc[m][i] * a + c, 0.f);
        hs[row * 120 + n] = (__bf16)v;
      }
  }
}

// h1 = relu(a1*(mx0 + v_r*w0y_n) + c1), v_r = ay*y_r + cy  (rank-1 y-column fixup)
__device__ __forceinline__ void write_h1(__bf16* hs, const f32x16* acc,
                                         float a, float c, float ay, float cy,
                                         float w0yn, int n, int half, const float* ysl) {
  if (n < 112) {
#pragma unroll
    for (int m = 0; m < 2; ++m)
#pragma unroll
      for (int i = 0; i < 16; ++i) {
        int row = m * 32 + (i & 3) + 8 * (i >> 2) + 4 * half;
        float add = (ay * ysl[row] + cy) * w0yn;
        float v = fmaxf((acc[m][i] + add) * a + c, 0.f);
        hs[row * 120 + n] = (__bf16)v;
      }
  }
}

__device__ __forceinline__ void write_z(float* zsl, const f32x16* acc,
                                        float a, float c, int n, int half) {
  if (n < DD) {
#pragma unroll
    for (int m = 0; m < 2; ++m)
#pragma unroll
      for (int i = 0; i < 16; ++i) {
        int row = m * 32 + (i & 3) + 8 * (i >> 2) + 4 * half;
        zsl[row * 104 + n] = acc[m][i] * a + c;
      }
  }
}

__global__ __launch_bounds__(NT) void bsde_kernel(Params p) {
  __shared__ float xs[ROWS * 104];
  __shared__ float zs[ROWS * 104];
  __shared__ float dws[ROWS * 104];
  __shared__ float ys[ROWS];
  __shared__ float us[ROWS];
  __shared__ __bf16 hsb[ROWS * 120];
  __shared__ float aS[128], cS[128];

  const int tid  = threadIdx.x;
  const int lane = tid & 63;
  const int wv   = tid >> 6;
  const int col  = lane & 31;
  const int half = lane >> 5;
  const int n    = wv * 32 + col;
  const int b0   = blockIdx.x * ROWS;

  // ---- init persistent state ----
  {
    float z0 = p.zini[0];
    for (int i = tid; i < ROWS * 104; i += NT) { xs[i] = 1.57079632679f; zs[i] = z0; }
    for (int i = tid; i < ROWS * 120; i += NT) hsb[i] = (__bf16)0.f;
    if (tid < ROWS) ys[tid] = p.yini[0];
  }
  for (int idx = tid; idx < ROWS * 128; idx += NT) {
    int r = idx >> 7, d = idx & 127;
    if (d < DD) {
      const float* wr = p.W + (size_t)(b0 + r) * 6400 + d;
      dws[r * 104 + d] = wr[100] - wr[0];
    }
  }
  __syncthreads();

  int seg = 0;   // 190 total barriers: 1 bootstrap + 63*3
  float tB[7][8];
  float w0yn;

  // ===== bootstrap: X_0 update + x-stats barrier (Z) =====
  {
    // x-update with dw_0, y=yini; drift/u with ec_0
    int r = tid >> 2, l4 = tid & 3;
    float yr = ys[r];
    float ssum = 0.f;
#pragma unroll
    for (int i = 0; i < 25; ++i) {
      int d = l4 + 4 * i;
      float dw = dws[r * 104 + d];
      float xv = xs[r * 104 + d] + 0.3f * dw * yr;
      xs[r * 104 + d] = xv;
      ssum += __sinf(xv);
    }
    ssum += __shfl_down(ssum, 2, 4);
    ssum += __shfl_down(ssum, 1, 4);
    if (l4 == 0) {
      float ec = __expf(-0.3f);
      float tc = 0.1f * ssum;
      float drift = -0.1f * yr + 0.045f * ec * tc * tc * tc;
      us[r] = yr - drift * (1.f / 64.f);
    }
  }
  __syncthreads();
  {
    float* slot = p.slots + (seg % 3) * REGF;
    if (tid < DD) {
      float sm = 0.f, sq = 0.f;
      for (int r = 0; r < ROWS; ++r) { float v = xs[r * 104 + tid]; sm += v; sq += v * v; }
      atomicAdd(&slot[224 + tid], sm);
      atomicAdd(&slot[336 + tid], sq);
    }
    sync_arrive(p.cnts);
    issueB<DD, HH>(p.w0, n, half, tB);
    w0yn = (n < HH) ? p.w0[100 * 110 + n] : 0.f;
    sync_wait(p.cnts, (seg + 1) * GRP);
    if (blockIdx.x < 2)
      agent_st(&p.slots[((seg + 2) % 3) * REGF + (int)blockIdx.x * 256 + tid], 0.f);
    if (tid < DD) {
      float sm = agent_ld(&slot[224 + tid]);
      float sq = agent_ld(&slot[336 + tid]);
      float mean = sm * (1.f / 8192.f);
      float var  = fmaxf(sq * (1.f / 8192.f) - mean * mean, 0.f);
      float au = p.g0[tid] * rsqrtf(var + 1e-6f);
      aS[tid] = au; cS[tid] = p.b0[tid] - mean * au;
    }
    ++seg;
  }
  __syncthreads();

  for (int s = 0; s < NS; ++s) {
    // ---- (1) Y_s = u_s + sum_d z_{s-1}*dw_s ----
    {
      int r = tid >> 2, l4 = tid & 3;
      float zdw = 0.f;
#pragma unroll
      for (int i = 0; i < 25; ++i) {
        int d = l4 + 4 * i;
        zdw += zs[r * 104 + d] * dws[r * 104 + d];
      }
      zdw += __shfl_down(zdw, 2, 4);
      zdw += __shfl_down(zdw, 1, 4);
      if (l4 == 0) ys[r] = us[r] + zdw;
    }
    __syncthreads();
    float* Eslot = p.slots + (seg % 3) * REGF;
    if (tid < 64) {   // y-stat partials (scalars) -> E
      float v = ys[tid], v2 = v * v;
#pragma unroll
      for (int off = 32; off > 0; off >>= 1) {
        v  += __shfl_down(v, off);
        v2 += __shfl_down(v2, off);
      }
      if (tid == 0) { atomicAdd(&Eslot[336], v); atomicAdd(&Eslot[337], v2); }
    }
    // ---- (2) h0x = bn0_x(X_s)  (y column handled analytically) ----
    for (int idx = tid; idx < ROWS * 128; idx += NT) {
      int r = idx >> 7, d = idx & 127;
      if (d < DD) hsb[r * 120 + d] = (__bf16)(xs[r * 104 + d] * aS[d] + cS[d]);
    }
    __syncthreads();

    f32x16 acc[2];
    // ---- (3)(4) mx0 = h0x @ w0[0:100,:]; E barrier (y-scalars + BN1 partials) ----
    run_mfma2(hsb, tB, col, half, acc);
    frag3(acc, Eslot, n, half, ys);
    sync_arrive(p.cnts);
    issueB<HH, HH>(p.w1 + (size_t)s * 12100, n, half, tB);
    sync_wait(p.cnts, (seg + 1) * GRP);
    if (blockIdx.x < 2)
      agent_st(&p.slots[((seg + 2) % 3) * REGF + (int)blockIdx.x * 256 + tid], 0.f);
    float ay, cy, a1 = 0.f, c1 = 0.f;
    {
      float Sy  = agent_ld(&Eslot[336]);
      float Syy = agent_ld(&Eslot[337]);
      float my = Sy * (1.f / 8192.f);
      float vy = fmaxf(Syy * (1.f / 8192.f) - my * my, 0.f);
      float auy = p.g0[s * 101 + 100] * rsqrtf(vy + 1e-6f);
      ay = auy; cy = p.b0[s * 101 + 100] - my * auy;
      if (n < HH) {
        float G1 = agent_ld(&Eslot[n]);
        float G2 = agent_ld(&Eslot[112 + n]);
        float G3 = agent_ld(&Eslot[224 + n]);
        float Sv  = ay * Sy + 8192.f * cy;
        float Svv = ay * ay * Syy + 2.f * ay * cy * Sy + 8192.f * cy * cy;
        float w = w0yn;
        float S1 = G1 + w * Sv;
        float S2 = G2 + 2.f * w * (ay * G3 + cy * G1) + w * w * Svv;
        float mean = S1 * (1.f / 8192.f);
        float var  = fmaxf(S2 * (1.f / 8192.f) - mean * mean, 0.f);
        float au = p.g1[s * HH + n] * rsqrtf(var + 1e-6f);
        a1 = au; c1 = p.b1[s * HH + n] - mean * au;
      }
    }
    ++seg;
    // ---- (5) h1 = relu(bn1(m0)) with rank-1 y fixup ----
    write_h1(hsb, acc, a1, c1, ay, cy, w0yn, n, half, ys);
    __syncthreads();

    // ---- (6) mm1 = h1 @ w1; C barrier (BN2 stats) ----
    run_mfma2(hsb, tB, col, half, acc);
    float* Cslot = p.slots + (seg % 3) * REGF;
    frag2(acc, Cslot, n, HH, half);
    sync_arrive(p.cnts);
    issueB<HH, DD>(p.w2 + (size_t)s * 11000, n, half, tB);
    if (s + 1 < NS) {      // prefetch dw_{s+1} + next step's w0y under the barrier
      for (int idx = tid; idx < ROWS * 128; idx += NT) {
        int r = idx >> 7, d = idx & 127;
        if (d < DD) {
          const float* wr = p.W + (size_t)(b0 + r) * 6400 + (s + 1) * 100 + d;
          dws[r * 104 + d] = wr[100] - wr[0];
        }
      }
      w0yn = (n < HH) ? p.w0[(size_t)(s + 1) * 11110 + 11000 + n] : 0.f;
    }
    sync_wait(p.cnts, (seg + 1) * GRP);
    if (blockIdx.x < 2)
      agent_st(&p.slots[((seg + 2) % 3) * REGF + (int)blockIdx.x * 256 + tid], 0.f);
    float a2, c2;
    finalize2(Cslot, p.g2 + s * HH, p.b2 + s * HH, n, HH, 1.f, a2, c2);
    ++seg;
    // ---- (7) h2 = relu(bn2(mm1)); mm2 = h2 @ w2; D partials ----
    write_h(hsb, acc, a2, c2, n, half);
    __syncthreads();
    run_mfma2(hsb, tB, col, half, acc);
    float* Dslot = p.slots + (seg % 3) * REGF;
    frag2(acc, Dslot, n, DD, half);
    // ---- (8) pre-D: X_{s+1} update (dw_{s+1}; dw_62 reused at s=62), u, x-stats ----
    {
      int r = tid >> 2, l4 = tid & 3;
      float yr = ys[r];
      float ssum = 0.f;
#pragma unroll
      for (int i = 0; i < 25; ++i) {
        int d = l4 + 4 * i;
        float dw = dws[r * 104 + d];
        float xv = xs[r * 104 + d] + 0.3f * dw * yr;
        xs[r * 104 + d] = xv;
        ssum += __sinf(xv);
      }
      ssum += __shfl_down(ssum, 2, 4);
      ssum += __shfl_down(ssum, 1, 4);
      if (l4 == 0) {
        int ei = (s + 1 < NS) ? s + 1 : NS - 1;   // ref reuses ec[62] for the final update
        float ec = __expf(-0.3f * (1.f - (float)ei * (1.f / 64.f)));
        float tc = 0.1f * ssum;
        float drift = -0.1f * yr + 0.045f * ec * tc * tc * tc;
        us[r] = yr - drift * (1.f / 64.f);
      }
    }
    __syncthreads();
    if (tid < DD) {
      float sm = 0.f, sq = 0.f;
      for (int r = 0; r < ROWS; ++r) { float v = xs[r * 104 + tid]; sm += v; sq += v * v; }
      atomicAdd(&Dslot[224 + tid], sm);
      atomicAdd(&Dslot[336 + tid], sq);
    }
    sync_arrive(p.cnts);
    if (s + 1 < NS) issueB<DD, HH>(p.w0 + (size_t)(s + 1) * 11110, n, half, tB);
    sync_wait(p.cnts, (seg + 1) * GRP);
    if (blockIdx.x < 2)
      agent_st(&p.slots[((seg + 2) % 3) * REGF + (int)blockIdx.x * 256 + tid], 0.f);
    float a3, c3;
    finalize2(Dslot, p.g3 + s * DD, p.b3 + s * DD, n, DD, 0.01f, a3, c3);
    if (s + 1 < NS && tid < DD) {   // BN0-x coefs for step s+1
      float sm = agent_ld(&Dslot[224 + tid]);
      float sq = agent_ld(&Dslot[336 + tid]);
      float mean = sm * (1.f / 8192.f);
      float var  = fmaxf(sq * (1.f / 8192.f) - mean * mean, 0.f);
      float au = p.g0[(s + 1) * 101 + tid] * rsqrtf(var + 1e-6f);
      aS[tid] = au; cS[tid] = p.b0[(s + 1) * 101 + tid] - mean * au;
    }
    ++seg;
    // ---- (9) z_s = bn3(mm2)/100 ----
    write_z(zs, acc, a3, c3, n, half);
    __syncthreads();
  }

  // ---- epilogue: Y_final = u_63 + sum z_62*dw_62 ----
  {
    int r = tid >> 2, l4 = tid & 3;
    float zdw = 0.f;
#pragma unroll
    for (int i = 0; i < 25; ++i) {
      int d = l4 + 4 * i;
      zdw += zs[r * 104 + d] * dws[r * 104 + d];
    }
    zdw += __shfl_down(zdw, 2, 4);
    zdw += __shfl_down(zdw, 1, 4);
    if (l4 == 0) ys[r] = us[r] + zdw;
  }
  __syncthreads();

  // ---- outputs: x [8192,100] then y [8192,1] ----
  for (int idx = tid; idx < ROWS * 128; idx += NT) {
    int r = idx >> 7, d = idx & 127;
    if (d < DD) p.out[(size_t)(b0 + r) * 100 + d] = xs[r * 104 + d];
  }
  if (tid < ROWS) p.out[819200 + b0 + tid] = ys[tid];
}

extern "C" void kernel_launch(void* const* d_in, const int* in_sizes, int n_in,
                              void* d_out, int out_size, void* d_ws, size_t ws_size,
                              hipStream_t stream) {
  Params p;
  p.W    = (const float*)d_in[0];
  p.yini = (const float*)d_in[1];
  p.zini = (const float*)d_in[2];
  p.g0   = (const float*)d_in[3];  p.b0 = (const float*)d_in[4];
  p.g1   = (const float*)d_in[5];  p.b1 = (const float*)d_in[6];
  p.g2   = (const float*)d_in[7];  p.b2 = (const float*)d_in[8];
  p.g3   = (const float*)d_in[9];  p.b3 = (const float*)d_in[10];
  p.w0   = (const float*)d_in[11]; p.w1 = (const float*)d_in[12];
  p.w2   = (const float*)d_in[13];
  p.out   = (float*)d_out;
  p.slots = (float*)d_ws;
  p.cnts  = (int*)((char*)d_ws + (size_t)3 * REGF * 4);

  size_t zbytes = (size_t)3 * REGF * 4           // 3 rotating stats regions
                + (size_t)NGRP * 16 * 4;         // monotonic group counters
  hipMemsetAsync(d_ws, 0, zbytes, stream);
  bsde_kernel<<<dim3(NBLK), dim3(NT), 0, stream>>>(p);
}

// Round 5
// 3114.921 us; speedup vs baseline: 1.3799x; 1.0005x over previous
//
#include <hip/hip_runtime.h>
#include <cstdint>
#include <cstddef>

#define NBLK 128
#define NT   256
#define ROWS 64
#define DD   100
#define HH   110
#define NS   63
#define NGRP 16
#define GRP  (NBLK / NGRP)
#define REGF 512              // floats per stats region (3 rotating regions)

typedef __bf16 bf16x8 __attribute__((ext_vector_type(8)));
typedef float  f32x16 __attribute__((ext_vector_type(16)));

struct Params {
  const float* W; const float* yini; const float* zini;
  const float* g0; const float* b0; const float* g1; const float* b1;
  const float* g2; const float* b2; const float* g3; const float* b3;
  const float* w0; const float* w1; const float* w2;
  float* out; float* slots; int* gcnt; int* scnt; int* rel;
};

__device__ __forceinline__ float agent_ld(const float* p_) {
  return __hip_atomic_load(p_, __ATOMIC_RELAXED, __HIP_MEMORY_SCOPE_AGENT);
}
__device__ __forceinline__ void agent_st(float* p_, float v) {
  __hip_atomic_store(p_, v, __ATOMIC_RELAXED, __HIP_MEMORY_SCOPE_AGENT);
}

// ---- release-fan-out grid barrier ----
// Two-level arrive: 8 adds per group counter; group-last (old==8*(bar+1)-1) adds
// to super counter; global-last (old==16*(bar+1)-1) stores bar+1 to 16 release
// lines. Each block polls ONLY its group's release line (8 pollers/line) ->
// no poll congestion at the MALL. Stats visibility: every wave drains its
// vmem (vmcnt(0)) before __syncthreads, so all stats are MALL-acked before
// thread0's counter add; the release store is data-dependent on observing all
// adds; a waiter that sees bar+1 therefore sees all stats. Monotonic, no reset.
__device__ __forceinline__ void sync_arrive(int* gcnt, int* scnt, int* rel, int bar) {
  asm volatile("s_waitcnt vmcnt(0)" ::: "memory");
  __syncthreads();
  if (threadIdx.x == 0) {
    int g = blockIdx.x & (NGRP - 1);
    int old = __hip_atomic_fetch_add(&gcnt[g * 16], 1,
                                     __ATOMIC_RELAXED, __HIP_MEMORY_SCOPE_AGENT);
    if (old == GRP * (bar + 1) - 1) {
      int so = __hip_atomic_fetch_add(scnt, 1,
                                      __ATOMIC_RELAXED, __HIP_MEMORY_SCOPE_AGENT);
      if (so == NGRP * (bar + 1) - 1) {
#pragma unroll
        for (int i = 0; i < NGRP; ++i)
          __hip_atomic_store(&rel[i * 16], bar + 1,
                             __ATOMIC_RELAXED, __HIP_MEMORY_SCOPE_AGENT);
      }
    }
  }
}
__device__ __forceinline__ void sync_wait(const int* rel, int bar) {
  if (threadIdx.x == 0) {
    while (__hip_atomic_load(&rel[(blockIdx.x & (NGRP - 1)) * 16],
                             __ATOMIC_RELAXED, __HIP_MEMORY_SCOPE_AGENT) < bar + 1)
      __builtin_amdgcn_s_sleep(1);
  }
  __syncthreads();
  asm volatile("" ::: "memory");
}

// B-fragment global loads (w[k][n], masked to zero outside K x N)
template<int K, int N>
__device__ __forceinline__ void issueB(const float* wg, int n, int half, float (*t)[8]) {
#pragma unroll
  for (int c = 0; c < 7; ++c) {
#pragma unroll
    for (int j = 0; j < 8; ++j) {
      int k = c * 16 + half * 8 + j;
      t[c][j] = (k < K && n < N) ? wg[k * N + n] : 0.f;
    }
  }
}

__device__ __forceinline__ void run_mfma2(const __bf16* hs, const float (*t)[8],
                                          int col, int half, f32x16* acc) {
  acc[0] = (f32x16)(0.f);
  acc[1] = (f32x16)(0.f);
#pragma unroll
  for (int c = 0; c < 7; ++c) {
    bf16x8 bfv;
#pragma unroll
    for (int j = 0; j < 8; ++j) bfv[j] = (__bf16)t[c][j];
    bf16x8 a0 = *(const bf16x8*)(hs + col * 120 + c * 16 + half * 8);
    bf16x8 a1 = *(const bf16x8*)(hs + (32 + col) * 120 + c * 16 + half * 8);
    acc[0] = __builtin_amdgcn_mfma_f32_32x32x16_bf16(a0, bfv, acc[0], 0, 0, 0);
    acc[1] = __builtin_amdgcn_mfma_f32_32x32x16_bf16(a1, bfv, acc[1], 0, 0, 0);
  }
}

// sum/sumsq partials -> flat slot [n], [112+n]
__device__ __forceinline__ void frag2(const f32x16* acc, float* slot, int n, int N, int half) {
  float sm = 0.f, sq = 0.f;
#pragma unroll
  for (int m = 0; m < 2; ++m)
#pragma unroll
    for (int i = 0; i < 16; ++i) { float v = acc[m][i]; sm += v; sq += v * v; }
  sm += __shfl_xor(sm, 32);
  sq += __shfl_xor(sq, 32);
  if (half == 0 && n < N) {
    atomicAdd(&slot[n], sm);
    atomicAdd(&slot[112 + n], sq);
  }
}

// sum/sumsq/sum(m*y) partials -> [n],[112+n],[224+n]  (E barrier)
__device__ __forceinline__ void frag3(const f32x16* acc, float* slot, int n, int half,
                                      const float* ysl) {
  float sm = 0.f, sq = 0.f, sy = 0.f;
#pragma unroll
  for (int m = 0; m < 2; ++m)
#pragma unroll
    for (int i = 0; i < 16; ++i) {
      float v = acc[m][i];
      int row = m * 32 + (i & 3) + 8 * (i >> 2) + 4 * half;
      sm += v; sq += v * v; sy += v * ysl[row];
    }
  sm += __shfl_xor(sm, 32);
  sq += __shfl_xor(sq, 32);
  sy += __shfl_xor(sy, 32);
  if (half == 0 && n < HH) {
    atomicAdd(&slot[n], sm);
    atomicAdd(&slot[112 + n], sq);
    atomicAdd(&slot[224 + n], sy);
  }
}

__device__ __forceinline__ void finalize2(const float* slot, const float* gam,
                                          const float* bet, int n, int N, float scale,
                                          float& a, float& c) {
  a = 0.f; c = 0.f;
  if (n < N) {
    float sm = agent_ld(&slot[n]);
    float sq = agent_ld(&slot[112 + n]);
    float mean = sm * (1.f / 8192.f);
    float var  = fmaxf(sq * (1.f / 8192.f) - mean * mean, 0.f);
    float au = gam[n] * rsqrtf(var + 1e-6f);
    a = au * scale;
    c = (bet[n] - mean * au) * scale;
  }
}

__device__ __forceinline__ void write_h(__bf16* hs, const f32x16* acc,
                                        float a, float c, int n, int half) {
  if (n < 112) {
#pragma unroll
    for (int m = 0; m < 2; ++m)
#pragma unroll
      for (int i = 0; i < 16; ++i) {
        int row = m * 32 + (i & 3) + 8 * (i >> 2) + 4 * half;
        float v = fmaxf(acc[m][i] * a + c, 0.f);
        hs[row * 120 + n] = (__bf16)v;
      }
  }
}

// h1 = relu(a1*(mx0 + v_r*w0y_n) + c1), v_r = ay*y_r + cy  (rank-1 y-column fixup)
__device__ __forceinline__ void write_h1(__bf16* hs, const f32x16* acc,
                                         float a, float c, float ay, float cy,
                                         float w0yn, int n, int half, const float* ysl) {
  if (n < 112) {
#pragma unroll
    for (int m = 0; m < 2; ++m)
#pragma unroll
      for (int i = 0; i < 16; ++i) {
        int row = m * 32 + (i & 3) + 8 * (i >> 2) + 4 * half;
        float add = (ay * ysl[row] + cy) * w0yn;
        float v = fmaxf((acc[m][i] + add) * a + c, 0.f);
        hs[row * 120 + n] = (__bf16)v;
      }
  }
}

__device__ __forceinline__ void write_z(float* zsl, const f32x16* acc,
                                        float a, float c, int n, int half) {
  if (n < DD) {
#pragma unroll
    for (int m = 0; m < 2; ++m)
#pragma unroll
      for (int i = 0; i < 16; ++i) {
        int row = m * 32 + (i & 3) + 8 * (i >> 2) + 4 * half;
        zsl[row * 104 + n] = acc[m][i] * a + c;
      }
  }
}

__global__ __launch_bounds__(NT) void bsde_kernel(Params p) {
  __shared__ float xs[ROWS * 104];
  __shared__ float zs[ROWS * 104];
  __shared__ float dws[ROWS * 104];
  __shared__ float ys[ROWS];
  __shared__ float us[ROWS];
  __shared__ __bf16 hsb[ROWS * 120];
  __shared__ float aS[128], cS[128];
  __shared__ float syS[2];

  const int tid  = threadIdx.x;
  const int lane = tid & 63;
  const int wv   = tid >> 6;
  const int col  = lane & 31;
  const int half = lane >> 5;
  const int n    = wv * 32 + col;
  const int b0   = blockIdx.x * ROWS;

  // ---- init persistent state ----
  {
    float z0 = p.zini[0];
    for (int i = tid; i < ROWS * 104; i += NT) { xs[i] = 1.57079632679f; zs[i] = z0; }
    for (int i = tid; i < ROWS * 120; i += NT) hsb[i] = (__bf16)0.f;
    if (tid < ROWS) ys[tid] = p.yini[0];
  }
  for (int idx = tid; idx < ROWS * 128; idx += NT) {
    int r = idx >> 7, d = idx & 127;
    if (d < DD) {
      const float* wr = p.W + (size_t)(b0 + r) * 6400 + d;
      dws[r * 104 + d] = wr[100] - wr[0];
    }
  }
  __syncthreads();

  int seg = 0;   // 190 total barriers: 1 bootstrap + 63*3
  float tB[7][8];
  float w0yn;

  // ===== bootstrap: X_0 update + x-stats barrier (Z) =====
  {
    int r = tid >> 2, l4 = tid & 3;
    float yr = ys[r];
    float ssum = 0.f;
#pragma unroll
    for (int i = 0; i < 25; ++i) {
      int d = l4 + 4 * i;
      float dw = dws[r * 104 + d];
      float xv = xs[r * 104 + d] + 0.3f * dw * yr;
      xs[r * 104 + d] = xv;
      ssum += __sinf(xv);
    }
    ssum += __shfl_down(ssum, 2, 4);
    ssum += __shfl_down(ssum, 1, 4);
    if (l4 == 0) {
      float ec = __expf(-0.3f);
      float tc = 0.1f * ssum;
      float drift = -0.1f * yr + 0.045f * ec * tc * tc * tc;
      us[r] = yr - drift * (1.f / 64.f);
    }
  }
  __syncthreads();
  {
    float* slot = p.slots + (seg % 3) * REGF;
    if (tid < DD) {
      float sm = 0.f, sq = 0.f;
      for (int r = 0; r < ROWS; ++r) { float v = xs[r * 104 + tid]; sm += v; sq += v * v; }
      atomicAdd(&slot[224 + tid], sm);
      atomicAdd(&slot[336 + tid], sq);
    }
    sync_arrive(p.gcnt, p.scnt, p.rel, seg);
    issueB<DD, HH>(p.w0, n, half, tB);
    w0yn = (n < HH) ? p.w0[100 * 110 + n] : 0.f;
    sync_wait(p.rel, seg);
    if (blockIdx.x < 2)
      agent_st(&p.slots[((seg + 2) % 3) * REGF + (int)blockIdx.x * 256 + tid], 0.f);
    if (tid < DD) {
      float sm = agent_ld(&slot[224 + tid]);
      float sq = agent_ld(&slot[336 + tid]);
      float mean = sm * (1.f / 8192.f);
      float var  = fmaxf(sq * (1.f / 8192.f) - mean * mean, 0.f);
      float au = p.g0[tid] * rsqrtf(var + 1e-6f);
      aS[tid] = au; cS[tid] = p.b0[tid] - mean * au;
    }
    ++seg;
  }
  __syncthreads();

  for (int s = 0; s < NS; ++s) {
    // ---- (1) Y_s = u_s + sum_d z_{s-1}*dw_s ----
    {
      int r = tid >> 2, l4 = tid & 3;
      float zdw = 0.f;
#pragma unroll
      for (int i = 0; i < 25; ++i) {
        int d = l4 + 4 * i;
        zdw += zs[r * 104 + d] * dws[r * 104 + d];
      }
      zdw += __shfl_down(zdw, 2, 4);
      zdw += __shfl_down(zdw, 1, 4);
      if (l4 == 0) ys[r] = us[r] + zdw;
    }
    __syncthreads();
    float* Eslot = p.slots + (seg % 3) * REGF;
    if (tid < 64) {   // y-stat partials (scalars) -> E
      float v = ys[tid], v2 = v * v;
#pragma unroll
      for (int off = 32; off > 0; off >>= 1) {
        v  += __shfl_down(v, off);
        v2 += __shfl_down(v2, off);
      }
      if (tid == 0) { atomicAdd(&Eslot[336], v); atomicAdd(&Eslot[337], v2); }
    }
    // ---- (2) h0x = bn0_x(X_s)  (y column handled analytically) ----
    for (int idx = tid; idx < ROWS * 128; idx += NT) {
      int r = idx >> 7, d = idx & 127;
      if (d < DD) hsb[r * 120 + d] = (__bf16)(xs[r * 104 + d] * aS[d] + cS[d]);
    }
    __syncthreads();

    f32x16 acc[2];
    // ---- (3)(4) mx0 = h0x @ w0[0:100,:]; E barrier (y-scalars + BN1 partials) ----
    run_mfma2(hsb, tB, col, half, acc);
    frag3(acc, Eslot, n, half, ys);
    sync_arrive(p.gcnt, p.scnt, p.rel, seg);
    issueB<HH, HH>(p.w1 + (size_t)s * 12100, n, half, tB);
    sync_wait(p.rel, seg);
    if (blockIdx.x < 2)
      agent_st(&p.slots[((seg + 2) % 3) * REGF + (int)blockIdx.x * 256 + tid], 0.f);
    // y-scalar lane-collapse: ONE uncached load of the shared line, LDS broadcast
    if (tid == 0) { syS[0] = agent_ld(&Eslot[336]); syS[1] = agent_ld(&Eslot[337]); }
    __syncthreads();
    float ay, cy, a1 = 0.f, c1 = 0.f;
    {
      float Sy  = syS[0];
      float Syy = syS[1];
      float my = Sy * (1.f / 8192.f);
      float vy = fmaxf(Syy * (1.f / 8192.f) - my * my, 0.f);
      float auy = p.g0[s * 101 + 100] * rsqrtf(vy + 1e-6f);
      ay = auy; cy = p.b0[s * 101 + 100] - my * auy;
      if (n < HH) {
        float G1 = agent_ld(&Eslot[n]);
        float G2 = agent_ld(&Eslot[112 + n]);
        float G3 = agent_ld(&Eslot[224 + n]);
        float Sv  = ay * Sy + 8192.f * cy;
        float Svv = ay * ay * Syy + 2.f * ay * cy * Sy + 8192.f * cy * cy;
        float w = w0yn;
        float S1 = G1 + w * Sv;
        float S2 = G2 + 2.f * w * (ay * G3 + cy * G1) + w * w * Svv;
        float mean = S1 * (1.f / 8192.f);
        float var  = fmaxf(S2 * (1.f / 8192.f) - mean * mean, 0.f);
        float au = p.g1[s * HH + n] * rsqrtf(var + 1e-6f);
        a1 = au; c1 = p.b1[s * HH + n] - mean * au;
      }
    }
    ++seg;
    // ---- (5) h1 = relu(bn1(m0)) with rank-1 y fixup ----
    write_h1(hsb, acc, a1, c1, ay, cy, w0yn, n, half, ys);
    __syncthreads();

    // ---- (6) mm1 = h1 @ w1; C barrier (BN2 stats) ----
    run_mfma2(hsb, tB, col, half, acc);
    float* Cslot = p.slots + (seg % 3) * REGF;
    frag2(acc, Cslot, n, HH, half);
    sync_arrive(p.gcnt, p.scnt, p.rel, seg);
    issueB<HH, DD>(p.w2 + (size_t)s * 11000, n, half, tB);
    if (s + 1 < NS) {      // prefetch dw_{s+1} + next step's w0y under the barrier
      for (int idx = tid; idx < ROWS * 128; idx += NT) {
        int r = idx >> 7, d = idx & 127;
        if (d < DD) {
          const float* wr = p.W + (size_t)(b0 + r) * 6400 + (s + 1) * 100 + d;
          dws[r * 104 + d] = wr[100] - wr[0];
        }
      }
      w0yn = (n < HH) ? p.w0[(size_t)(s + 1) * 11110 + 11000 + n] : 0.f;
    }
    sync_wait(p.rel, seg);
    if (blockIdx.x < 2)
      agent_st(&p.slots[((seg + 2) % 3) * REGF + (int)blockIdx.x * 256 + tid], 0.f);
    float a2, c2;
    finalize2(Cslot, p.g2 + s * HH, p.b2 + s * HH, n, HH, 1.f, a2, c2);
    ++seg;
    // ---- (7) h2 = relu(bn2(mm1)); mm2 = h2 @ w2; D partials ----
    write_h(hsb, acc, a2, c2, n, half);
    __syncthreads();
    run_mfma2(hsb, tB, col, half, acc);
    float* Dslot = p.slots + (seg % 3) * REGF;
    frag2(acc, Dslot, n, DD, half);
    // ---- (8) pre-D: X_{s+1} update (dw_{s+1}; dw_62 reused at s=62), u, x-stats ----
    {
      int r = tid >> 2, l4 = tid & 3;
      float yr = ys[r];
      float ssum = 0.f;
#pragma unroll
      for (int i = 0; i < 25; ++i) {
        int d = l4 + 4 * i;
        float dw = dws[r * 104 + d];
        float xv = xs[r * 104 + d] + 0.3f * dw * yr;
        xs[r * 104 + d] = xv;
        ssum += __sinf(xv);
      }
      ssum += __shfl_down(ssum, 2, 4);
      ssum += __shfl_down(ssum, 1, 4);
      if (l4 == 0) {
        int ei = (s + 1 < NS) ? s + 1 : NS - 1;   // ref reuses ec[62] for the final update
        float ec = __expf(-0.3f * (1.f - (float)ei * (1.f / 64.f)));
        float tc = 0.1f * ssum;
        float drift = -0.1f * yr + 0.045f * ec * tc * tc * tc;
        us[r] = yr - drift * (1.f / 64.f);
      }
    }
    __syncthreads();
    if (tid < DD) {
      float sm = 0.f, sq = 0.f;
      for (int r = 0; r < ROWS; ++r) { float v = xs[r * 104 + tid]; sm += v; sq += v * v; }
      atomicAdd(&Dslot[224 + tid], sm);
      atomicAdd(&Dslot[336 + tid], sq);
    }
    sync_arrive(p.gcnt, p.scnt, p.rel, seg);
    if (s + 1 < NS) issueB<DD, HH>(p.w0 + (size_t)(s + 1) * 11110, n, half, tB);
    sync_wait(p.rel, seg);
    if (blockIdx.x < 2)
      agent_st(&p.slots[((seg + 2) % 3) * REGF + (int)blockIdx.x * 256 + tid], 0.f);
    float a3, c3;
    finalize2(Dslot, p.g3 + s * DD, p.b3 + s * DD, n, DD, 0.01f, a3, c3);
    if (s + 1 < NS && tid < DD) {   // BN0-x coefs for step s+1
      float sm = agent_ld(&Dslot[224 + tid]);
      float sq = agent_ld(&Dslot[336 + tid]);
      float mean = sm * (1.f / 8192.f);
      float var  = fmaxf(sq * (1.f / 8192.f) - mean * mean, 0.f);
      float au = p.g0[(s + 1) * 101 + tid] * rsqrtf(var + 1e-6f);
      aS[tid] = au; cS[tid] = p.b0[(s + 1) * 101 + tid] - mean * au;
    }
    ++seg;
    // ---- (9) z_s = bn3(mm2)/100 ----
    write_z(zs, acc, a3, c3, n, half);
    __syncthreads();
  }

  // ---- epilogue: Y_final = u_63 + sum z_62*dw_62 ----
  {
    int r = tid >> 2, l4 = tid & 3;
    float zdw = 0.f;
#pragma unroll
    for (int i = 0; i < 25; ++i) {
      int d = l4 + 4 * i;
      zdw += zs[r * 104 + d] * dws[r * 104 + d];
    }
    zdw += __shfl_down(zdw, 2, 4);
    zdw += __shfl_down(zdw, 1, 4);
    if (l4 == 0) ys[r] = us[r] + zdw;
  }
  __syncthreads();

  // ---- outputs: x [8192,100] then y [8192,1] ----
  for (int idx = tid; idx < ROWS * 128; idx += NT) {
    int r = idx >> 7, d = idx & 127;
    if (d < DD) p.out[(size_t)(b0 + r) * 100 + d] = xs[r * 104 + d];
  }
  if (tid < ROWS) p.out[819200 + b0 + tid] = ys[tid];
}

extern "C" void kernel_launch(void* const* d_in, const int* in_sizes, int n_in,
                              void* d_out, int out_size, void* d_ws, size_t ws_size,
                              hipStream_t stream) {
  Params p;
  p.W    = (const float*)d_in[0];
  p.yini = (const float*)d_in[1];
  p.zini = (const float*)d_in[2];
  p.g0   = (const float*)d_in[3];  p.b0 = (const float*)d_in[4];
  p.g1   = (const float*)d_in[5];  p.b1 = (const float*)d_in[6];
  p.g2   = (const float*)d_in[7];  p.b2 = (const float*)d_in[8];
  p.g3   = (const float*)d_in[9];  p.b3 = (const float*)d_in[10];
  p.w0   = (const float*)d_in[11]; p.w1 = (const float*)d_in[12];
  p.w2   = (const float*)d_in[13];
  p.out   = (float*)d_out;
  p.slots = (float*)d_ws;
  char* base = (char*)d_ws + (size_t)3 * REGF * 4;   // 6144 B of stats regions
  p.gcnt = (int*)base;                                // 16 x 64B = 1024 B
  p.scnt = (int*)(base + 1024);                       // 64 B
  p.rel  = (int*)(base + 1088);                       // 16 x 64B = 1024 B

  size_t zbytes = (size_t)3 * REGF * 4 + 1024 + 64 + 1024;
  hipMemsetAsync(d_ws, 0, zbytes, stream);
  bsde_kernel<<<dim3(NBLK), dim3(NT), 0, stream>>>(p);
}